// Round 9
// baseline (266.329 us; speedup 1.0000x reference)
//
#include <hip/hip_runtime.h>
#include <hip/hip_bf16.h>
#include <math.h>

#define NJ 24
#define NV 6890
#define NVP 6912          // padded vertex count (27*256)
#define NPRIME 20736      // 3*NVP, GEMM N dimension
#define NT 1296           // NPRIME/16 n-tiles
#define KDIM 224          // padded K: [0..9]=betas/sd, [10]=1/vt, [11..217]=lrot/pd, rest 0

__constant__ int c_par[24] = {0, 0, 0, 0, 1, 2, 3, 4, 5, 6, 7, 8, 9, 9, 9,
                              12, 13, 14, 16, 17, 18, 19, 20, 21};

typedef __attribute__((ext_vector_type(8))) short short8;
typedef __attribute__((ext_vector_type(4))) float float4v;

__device__ __forceinline__ unsigned short f2b(float x) {
    __hip_bfloat16 h = __float2bfloat16(x);
    return *reinterpret_cast<unsigned short*>(&h);
}
__device__ __forceinline__ float b2f(unsigned short u) {
    unsigned int w = ((unsigned int)u) << 16;
    return __uint_as_float(w);
}

// ---------------------------------------------------------------------------
// T: pack kernel (R4 version: B2 + w_t + jr_t).
__global__ void t_pack(const float* __restrict__ pd,
                       const float* __restrict__ W,
                       const float* __restrict__ jr,
                       const float* __restrict__ sd,
                       const float* __restrict__ vt,
                       unsigned short* __restrict__ B2,
                       float* __restrict__ w_t,
                       float* __restrict__ jr_t) {
    int idx = blockIdx.x * 256 + threadIdx.x;
    const int B2_N = 7 * NT * 16 * 32;        // 4,644,864
    if (idx < B2_N) {
        int kk = idx & 31;
        int ln = (idx >> 5) & 15;
        int rest = idx >> 9;                  // nt + NT*kc
        int nt = rest % NT, kc = rest / NT;
        int k = kc * 32 + kk;
        int np = nt * 16 + ln;
        int c = np / NVP, v = np - c * NVP;
        float val = 0.f;
        if (v < NV) {
            if (k < 10)       val = sd[(size_t)v * 30 + c * 10 + k];
            else if (k == 10) val = vt[v * 3 + c];
            else if (k < 218) val = pd[(size_t)v * 621 + c * 207 + (k - 11)];
        }
        B2[idx] = f2b(val);
        return;
    }
    idx -= B2_N;
    if (idx < 24 * NVP) {
        int j = idx / NVP, v = idx % NVP;
        if (v < NV) w_t[(size_t)j * NVP + v] = W[(size_t)v * 24 + j];
        return;
    }
    idx -= 24 * NVP;
    if (idx < 24 * NVP) {
        int j = idx / NVP, v = idx % NVP;
        if (v < NV) jr_t[(size_t)j * NVP + v] = jr[(size_t)v * 24 + j];
        return;
    }
}

// ---------------------------------------------------------------------------
// K1: fold J_regressor into shapedirs / v_template.  (R4: separate, grid (72,8))
__global__ void k1_regress(const float* __restrict__ Jreg,
                           const float* __restrict__ sd,
                           const float* __restrict__ vt,
                           float* __restrict__ SD_Jp) {
    const int jc = blockIdx.x;            // 0..71
    const int ch = blockIdx.y;            // 0..7
    const int j = jc / 3, c = jc % 3;
    const int v0 = ch * 864;
    int vend = v0 + 864; if (vend > NV) vend = NV;

    float acc[11];
#pragma unroll
    for (int k = 0; k < 11; k++) acc[k] = 0.f;

    for (int v = v0 + threadIdx.x; v < vend; v += 256) {
        float r = Jreg[j * NV + v];
        const float* sp = sd + (size_t)v * 30 + c * 10;
#pragma unroll
        for (int k = 0; k < 10; k++) acc[k] += r * sp[k];
        acc[10] += r * vt[v * 3 + c];
    }
#pragma unroll
    for (int k = 0; k < 11; k++) {
        float x = acc[k];
        for (int off = 32; off > 0; off >>= 1) x += __shfl_down(x, off);
        acc[k] = x;
    }
    __shared__ float red[4][11];
    int lane = threadIdx.x & 63, wid = threadIdx.x >> 6;
    if (lane == 0) {
#pragma unroll
        for (int k = 0; k < 11; k++) red[wid][k] = acc[k];
    }
    __syncthreads();
    if (threadIdx.x == 0) {
        float* op = SD_Jp + ((size_t)ch * 72 + jc) * 11;
#pragma unroll
        for (int k = 0; k < 11; k++)
            op[k] = red[0][k] + red[1][k] + red[2][k] + red[3][k];
    }
}

// ---------------------------------------------------------------------------
// K2: per-sample joints + rodrigues + FK + A_bf pack.  (unchanged)
__global__ void k2_fk(const float* __restrict__ betas,
                      const float* __restrict__ thetas,
                      const float* __restrict__ SD_Jp,
                      float* __restrict__ Gout,
                      unsigned short* __restrict__ A_bf,
                      float* __restrict__ outj) {
    int n = blockIdx.x;
    int j = threadIdx.x;

    __shared__ float bsh[10];
    __shared__ float Jl[24][3];
    __shared__ float A[24][12];
    __shared__ float Gs[24][12];
    __shared__ float lr[208];     // lrotmin staging for A_bf pack

    if (threadIdx.x < 10) bsh[threadIdx.x] = betas[n * 10 + threadIdx.x];
    if (threadIdx.x == 0) lr[207] = 0.f;
    for (int q = threadIdx.x; q < 72; q += 64) outj[(size_t)n * 72 + q] = 0.f;
    __syncthreads();

    if (j < 24) {
#pragma unroll
        for (int c = 0; c < 3; c++) {
            float acc[11];
#pragma unroll
            for (int k = 0; k < 11; k++) acc[k] = 0.f;
#pragma unroll
            for (int ch = 0; ch < 8; ch++) {
                const float* pp = SD_Jp + ((size_t)ch * 72 + j * 3 + c) * 11;
#pragma unroll
                for (int k = 0; k < 11; k++) acc[k] += pp[k];
            }
            float s = acc[10];
#pragma unroll
            for (int k = 0; k < 10; k++) s += bsh[k] * acc[k];
            Jl[j][c] = s;
        }
    }
    __syncthreads();

    if (j < 24) {
        float rx = thetas[n * 72 + j * 3 + 0];
        float ry = thetas[n * 72 + j * 3 + 1];
        float rz = thetas[n * 72 + j * 3 + 2];
        float th = sqrtf(rx * rx + ry * ry + rz * rz) + 1e-8f;
        float inv = 1.f / th;
        float hx = rx * inv, hy = ry * inv, hz = rz * inv;
        float ct = cosf(th), st = sinf(th), omc = 1.f - ct;
        float R[3][3];
        R[0][0] = ct + omc * hx * hx;
        R[0][1] = omc * hx * hy - st * hz;
        R[0][2] = omc * hx * hz + st * hy;
        R[1][0] = omc * hx * hy + st * hz;
        R[1][1] = ct + omc * hy * hy;
        R[1][2] = omc * hy * hz - st * hx;
        R[2][0] = omc * hx * hz - st * hy;
        R[2][1] = omc * hy * hz + st * hx;
        R[2][2] = ct + omc * hz * hz;

        if (j >= 1) {
            float* lp = &lr[(j - 1) * 9];
#pragma unroll
            for (int r = 0; r < 3; r++)
#pragma unroll
                for (int c = 0; c < 3; c++)
                    lp[r * 3 + c] = R[r][c] - ((r == c) ? 1.f : 0.f);
        }
        float tx, ty, tz;
        if (j == 0) { tx = Jl[0][0]; ty = Jl[0][1]; tz = Jl[0][2]; }
        else {
            int p = c_par[j];
            tx = Jl[j][0] - Jl[p][0];
            ty = Jl[j][1] - Jl[p][1];
            tz = Jl[j][2] - Jl[p][2];
        }
#pragma unroll
        for (int r = 0; r < 3; r++) {
            A[j][r * 4 + 0] = R[r][0];
            A[j][r * 4 + 1] = R[r][1];
            A[j][r * 4 + 2] = R[r][2];
        }
        A[j][3] = tx; A[j][7] = ty; A[j][11] = tz;
    }
    __syncthreads();

    if (threadIdx.x == 0) {
#pragma unroll
        for (int q = 0; q < 12; q++) Gs[0][q] = A[0][q];
        for (int i = 1; i < 24; i++) {
            int p = c_par[i];
#pragma unroll
            for (int r = 0; r < 3; r++) {
                float g0 = Gs[p][r * 4 + 0], g1 = Gs[p][r * 4 + 1];
                float g2 = Gs[p][r * 4 + 2], g3 = Gs[p][r * 4 + 3];
#pragma unroll
                for (int c = 0; c < 4; c++) {
                    float s = g0 * A[i][0 * 4 + c] + g1 * A[i][1 * 4 + c] +
                              g2 * A[i][2 * 4 + c];
                    if (c == 3) s += g3;
                    Gs[i][r * 4 + c] = s;
                }
            }
        }
    }
    for (int k = threadIdx.x; k < KDIM; k += 64) {
        float val;
        if (k < 10)       val = bsh[k];
        else if (k == 10) val = 1.f;
        else if (k < 218) val = lr[k - 11];
        else              val = 0.f;
        A_bf[(size_t)n * KDIM + k] = f2b(val);
    }
    __syncthreads();

    if (j < 24) {
        float jx = Jl[j][0], jy = Jl[j][1], jz = Jl[j][2];
        float* gp = Gout + (size_t)n * 288 + j * 12;
#pragma unroll
        for (int r = 0; r < 3; r++) {
            float r0 = Gs[j][r * 4 + 0], r1 = Gs[j][r * 4 + 1];
            float r2 = Gs[j][r * 4 + 2], t = Gs[j][r * 4 + 3];
            gp[r * 4 + 0] = r0;
            gp[r * 4 + 1] = r1;
            gp[r * 4 + 2] = r2;
            gp[r * 4 + 3] = t - (r0 * jx + r1 * jy + r2 * jz);
        }
    }
}

// ---------------------------------------------------------------------------
// K3G: MFMA GEMM  (R4 version, 64-sample m-blocks: B2 streamed only 8x)
__global__ void __launch_bounds__(256)
k3g(const unsigned short* __restrict__ A_bf,
    const unsigned short* __restrict__ B2,
    unsigned short* __restrict__ vposed) {
    const int wave = threadIdx.x >> 6, lane = threadIdx.x & 63;
    const int ln = lane & 15, q = lane >> 4;
    const int m0 = blockIdx.y * 64 + wave * 16;
    const int nt0 = blockIdx.x * 12;

    short8 a[7];
    {
        const int row = m0 + ln;
#pragma unroll
        for (int kc = 0; kc < 7; kc++)
            a[kc] = *(const short8*)(A_bf + (size_t)row * KDIM + kc * 32 + q * 8);
    }
    for (int t = 0; t < 12; t++) {
        const int nt = nt0 + t;
        float4v acc = {0.f, 0.f, 0.f, 0.f};
#pragma unroll
        for (int kc = 0; kc < 7; kc++) {
            short8 b = *(const short8*)(B2 +
                (((size_t)kc * NT + nt) * 16 + ln) * 32 + q * 8);
            acc = __builtin_amdgcn_mfma_f32_16x16x32_bf16(a[kc], b, acc, 0, 0, 0);
        }
        const int np = nt * 16 + ln;
#pragma unroll
        for (int r = 0; r < 4; r++) {
            int m = m0 + q * 4 + r;
            vposed[(size_t)m * NPRIME + np] = f2b(acc[r]);
        }
    }
}

// ---------------------------------------------------------------------------
// K3L: LBS.  (R4 best version: 4 verts/lane, no-LDS, readfirstlane sample,
// grid (128,27).)
__global__ void __launch_bounds__(256)
k3l(const float* __restrict__ trans,
    const unsigned short* __restrict__ vposed,
    const float* __restrict__ w_t,
    const float* __restrict__ G_ws,
    float* __restrict__ out) {
    const int tid = threadIdx.x;
    const int lane = tid & 63;
    const int nu = __builtin_amdgcn_readfirstlane(blockIdx.x * 4 + (tid >> 6));
    const int v4 = blockIdx.y * 256 + lane * 4;

    const float* gp = G_ws + (size_t)nu * 288;
    const float t0 = trans[nu * 3 + 0];
    const float t1 = trans[nu * 3 + 1];
    const float t2 = trans[nu * 3 + 2];

    float vp[3][4];
#pragma unroll
    for (int c = 0; c < 3; c++) {
        uint2 u = *(const uint2*)(vposed + (size_t)nu * NPRIME + c * NVP + v4);
        vp[c][0] = b2f((unsigned short)(u.x & 0xFFFF));
        vp[c][1] = b2f((unsigned short)(u.x >> 16));
        vp[c][2] = b2f((unsigned short)(u.y & 0xFFFF));
        vp[c][3] = b2f((unsigned short)(u.y >> 16));
    }

    float o[3][4];
#pragma unroll
    for (int c = 0; c < 3; c++)
#pragma unroll
        for (int i = 0; i < 4; i++) o[c][i] = 0.f;

    for (int j = 0; j < NJ; j++) {
        float4 w4 = *(const float4*)(w_t + (size_t)j * NVP + v4);
        float wv[4] = {w4.x, w4.y, w4.z, w4.w};
        const float4* g4 = (const float4*)(gp + j * 12);    // uniform loads
        float4 g0 = g4[0], g1 = g4[1], g2 = g4[2];
#pragma unroll
        for (int i = 0; i < 4; i++) {
            float x = vp[0][i], y = vp[1][i], z = vp[2][i];
            float r0 = g0.x * x + g0.y * y + g0.z * z + g0.w;
            float r1 = g1.x * x + g1.y * y + g1.z * z + g1.w;
            float r2 = g2.x * x + g2.y * y + g2.z * z + g2.w;
            o[0][i] += wv[i] * r0;
            o[1][i] += wv[i] * r1;
            o[2][i] += wv[i] * r2;
        }
    }

    {
        float* op = out + ((size_t)nu * NV + v4) * 3;
#pragma unroll
        for (int i = 0; i < 4; i++) {
            if (v4 + i < NV) {
                op[i * 3 + 0] = o[0][i] + t0;
                op[i * 3 + 1] = o[1][i] + t1;
                op[i * 3 + 2] = o[2][i] + t2;
            }
        }
    }
}

// ---------------------------------------------------------------------------
// K4: joints reduction.  REWRITTEN to amortize jr_t (was: 2048 blocks x
// 166 KB jr_t region = ~340 MB L2 traffic/dispatch, jr_t re-read per sample).
// Now: 512-thread blocks, grid (N/8, 27); each block LDS-stages
// jr_t[24][256] (24.5 KB) ONCE, 8 waves = 8 samples x 4 joint-groups
// (wave w: jgroup w&3, samples nbase + (w>>2)*4 .. +3).
// jr_t traffic 340 -> 42 MB; result chunk (24 KB/block) L1-resident.
__global__ void __launch_bounds__(512)
k4_joints_t(const float* __restrict__ result,
            const float* __restrict__ jr_t,
            float* __restrict__ outj) {
    __shared__ float jr_lds[24][256];
    const int ch = blockIdx.y;
    const int vbase = ch * 256;
    const int tid = threadIdx.x;

    for (int f = tid * 4; f < 24 * 256; f += 512 * 4) {
        int j = f >> 8, vv = f & 255;
        *(float4*)&jr_lds[j][vv] =
            *(const float4*)(jr_t + (size_t)j * NVP + vbase + vv);
    }
    __syncthreads();

    const int lane = tid & 63, w = tid >> 6;
    const int j0 = (w & 3) * 6;
    const int nbase = blockIdx.x * 8 + (w >> 2) * 4;

    for (int k = 0; k < 4; k++) {
        const int n = nbase + k;
        const float* rb = result + (size_t)n * NV * 3;
        float acc[18];
#pragma unroll
        for (int q = 0; q < 18; q++) acc[q] = 0.f;

#pragma unroll
        for (int it = 0; it < 4; it++) {
            int vr = it * 64 + lane;
            int v = vbase + vr;
            if (v < NV) {
                float r0 = rb[v * 3 + 0], r1 = rb[v * 3 + 1], r2 = rb[v * 3 + 2];
#pragma unroll
                for (int jj = 0; jj < 6; jj++) {
                    float wv = jr_lds[j0 + jj][vr];
                    acc[jj * 3 + 0] += wv * r0;
                    acc[jj * 3 + 1] += wv * r1;
                    acc[jj * 3 + 2] += wv * r2;
                }
            }
        }
#pragma unroll
        for (int q = 0; q < 18; q++) {
            float x = acc[q];
            for (int off = 32; off > 0; off >>= 1) x += __shfl_down(x, off);
            acc[q] = x;
        }
        if (lane == 0) {
#pragma unroll
            for (int q = 0; q < 18; q++)
                atomicAdd(&outj[(size_t)n * 72 + j0 * 3 + q], acc[q]);
        }
    }
}

// ---------------------------------------------------------------------------
extern "C" void kernel_launch(void* const* d_in, const int* in_sizes, int n_in,
                              void* d_out, int out_size, void* d_ws, size_t ws_size,
                              hipStream_t stream) {
    const float* betas     = (const float*)d_in[0];
    const float* thetas    = (const float*)d_in[1];
    const float* trans     = (const float*)d_in[2];
    const float* v_templ   = (const float*)d_in[3];
    const float* shapedirs = (const float*)d_in[4];
    const float* posedirs  = (const float*)d_in[5];
    const float* Jreg      = (const float*)d_in[6];
    const float* jointreg  = (const float*)d_in[7];
    const float* weights   = (const float*)d_in[8];

    float* out = (float*)d_out;       // fp32: result [N,V,3] then joints [N,24,3]
    const int N = in_sizes[0] / 10;   // 512

    // ws layout
    float* ws    = (float*)d_ws;
    float* SD_Jp = ws;                                   // 8*72*11 = 6336 (+pad) -> 6400
    float* G_ws  = ws + 6400;                            // N*288
    float* w_t   = G_ws + (size_t)N * 288;               // 24*NVP
    float* jr_t  = w_t + 24 * NVP;                       // 24*NVP
    unsigned short* A_bf = (unsigned short*)(jr_t + 24 * NVP);      // 512*224
    unsigned short* B2   = A_bf + (size_t)512 * KDIM;               // 7*NT*512
    unsigned short* vpos = B2 + (size_t)7 * NT * 512;               // 512*NPRIME

    float* outj = out + (size_t)N * NV * 3;

    dim3 g1(72, 8);
    k1_regress<<<g1, 256, 0, stream>>>(Jreg, shapedirs, v_templ, SD_Jp);
    k2_fk<<<N, 64, 0, stream>>>(betas, thetas, SD_Jp, G_ws, A_bf, outj);

    const int B2_N = 7 * NT * 16 * 32;
    int t_total = B2_N + (24 + 24) * NVP;
    t_pack<<<(t_total + 255) / 256, 256, 0, stream>>>(
        posedirs, weights, jointreg, shapedirs, v_templ,
        B2, w_t, jr_t);

    dim3 gg(NT / 12, N / 64);     // (108, 8)
    k3g<<<gg, 256, 0, stream>>>(A_bf, B2, vpos);

    dim3 gl(N / 4, NVP / 256);    // (128, 27) = 3456 blocks
    k3l<<<gl, 256, 0, stream>>>(trans, vpos, w_t, G_ws, out);

    dim3 g4(N / 8, 27);           // (64, 27) = 1728 blocks, 512 thr
    k4_joints_t<<<g4, 512, 0, stream>>>(out, jr_t, outj);
}

// Round 10
// 198.697 us; speedup vs baseline: 1.3404x; 1.3404x over previous
//
#include <hip/hip_runtime.h>
#include <hip/hip_bf16.h>
#include <math.h>

#define NJ 24
#define NV 6890
#define NVP 6912          // padded vertex count (27*256)
#define NPRIME 20736      // 3*NVP, GEMM N dimension
#define NT 1296           // NPRIME/16 n-tiles
#define KDIM 224          // padded K: [0..9]=betas/sd, [10]=1/vt, [11..217]=lrot/pd, rest 0

__constant__ int c_par[24] = {0, 0, 0, 0, 1, 2, 3, 4, 5, 6, 7, 8, 9, 9, 9,
                              12, 13, 14, 16, 17, 18, 19, 20, 21};

typedef __attribute__((ext_vector_type(8))) short short8;
typedef __attribute__((ext_vector_type(4))) float float4v;

__device__ __forceinline__ unsigned short f2b(float x) {
    __hip_bfloat16 h = __float2bfloat16(x);
    return *reinterpret_cast<unsigned short*>(&h);
}
__device__ __forceinline__ float b2f(unsigned short u) {
    unsigned int w = ((unsigned int)u) << 16;
    return __uint_as_float(w);
}

// ---------------------------------------------------------------------------
// T: pack kernel (R4 version: B2 + w_t + jr_t).
__global__ void t_pack(const float* __restrict__ pd,
                       const float* __restrict__ W,
                       const float* __restrict__ jr,
                       const float* __restrict__ sd,
                       const float* __restrict__ vt,
                       unsigned short* __restrict__ B2,
                       float* __restrict__ w_t,
                       float* __restrict__ jr_t) {
    int idx = blockIdx.x * 256 + threadIdx.x;
    const int B2_N = 7 * NT * 16 * 32;        // 4,644,864
    if (idx < B2_N) {
        int kk = idx & 31;
        int ln = (idx >> 5) & 15;
        int rest = idx >> 9;                  // nt + NT*kc
        int nt = rest % NT, kc = rest / NT;
        int k = kc * 32 + kk;
        int np = nt * 16 + ln;
        int c = np / NVP, v = np - c * NVP;
        float val = 0.f;
        if (v < NV) {
            if (k < 10)       val = sd[(size_t)v * 30 + c * 10 + k];
            else if (k == 10) val = vt[v * 3 + c];
            else if (k < 218) val = pd[(size_t)v * 621 + c * 207 + (k - 11)];
        }
        B2[idx] = f2b(val);
        return;
    }
    idx -= B2_N;
    if (idx < 24 * NVP) {
        int j = idx / NVP, v = idx % NVP;
        if (v < NV) w_t[(size_t)j * NVP + v] = W[(size_t)v * 24 + j];
        return;
    }
    idx -= 24 * NVP;
    if (idx < 24 * NVP) {
        int j = idx / NVP, v = idx % NVP;
        if (v < NV) jr_t[(size_t)j * NVP + v] = jr[(size_t)v * 24 + j];
        return;
    }
}

// ---------------------------------------------------------------------------
// K1: fold J_regressor into shapedirs / v_template.  (R4: separate, grid (72,8))
__global__ void k1_regress(const float* __restrict__ Jreg,
                           const float* __restrict__ sd,
                           const float* __restrict__ vt,
                           float* __restrict__ SD_Jp) {
    const int jc = blockIdx.x;            // 0..71
    const int ch = blockIdx.y;            // 0..7
    const int j = jc / 3, c = jc % 3;
    const int v0 = ch * 864;
    int vend = v0 + 864; if (vend > NV) vend = NV;

    float acc[11];
#pragma unroll
    for (int k = 0; k < 11; k++) acc[k] = 0.f;

    for (int v = v0 + threadIdx.x; v < vend; v += 256) {
        float r = Jreg[j * NV + v];
        const float* sp = sd + (size_t)v * 30 + c * 10;
#pragma unroll
        for (int k = 0; k < 10; k++) acc[k] += r * sp[k];
        acc[10] += r * vt[v * 3 + c];
    }
#pragma unroll
    for (int k = 0; k < 11; k++) {
        float x = acc[k];
        for (int off = 32; off > 0; off >>= 1) x += __shfl_down(x, off);
        acc[k] = x;
    }
    __shared__ float red[4][11];
    int lane = threadIdx.x & 63, wid = threadIdx.x >> 6;
    if (lane == 0) {
#pragma unroll
        for (int k = 0; k < 11; k++) red[wid][k] = acc[k];
    }
    __syncthreads();
    if (threadIdx.x == 0) {
        float* op = SD_Jp + ((size_t)ch * 72 + jc) * 11;
#pragma unroll
        for (int k = 0; k < 11; k++)
            op[k] = red[0][k] + red[1][k] + red[2][k] + red[3][k];
    }
}

// ---------------------------------------------------------------------------
// K2: per-sample joints + rodrigues + FK + A_bf pack.  (unchanged)
__global__ void k2_fk(const float* __restrict__ betas,
                      const float* __restrict__ thetas,
                      const float* __restrict__ SD_Jp,
                      float* __restrict__ Gout,
                      unsigned short* __restrict__ A_bf,
                      float* __restrict__ outj) {
    int n = blockIdx.x;
    int j = threadIdx.x;

    __shared__ float bsh[10];
    __shared__ float Jl[24][3];
    __shared__ float A[24][12];
    __shared__ float Gs[24][12];
    __shared__ float lr[208];     // lrotmin staging for A_bf pack

    if (threadIdx.x < 10) bsh[threadIdx.x] = betas[n * 10 + threadIdx.x];
    if (threadIdx.x == 0) lr[207] = 0.f;
    for (int q = threadIdx.x; q < 72; q += 64) outj[(size_t)n * 72 + q] = 0.f;
    __syncthreads();

    if (j < 24) {
#pragma unroll
        for (int c = 0; c < 3; c++) {
            float acc[11];
#pragma unroll
            for (int k = 0; k < 11; k++) acc[k] = 0.f;
#pragma unroll
            for (int ch = 0; ch < 8; ch++) {
                const float* pp = SD_Jp + ((size_t)ch * 72 + j * 3 + c) * 11;
#pragma unroll
                for (int k = 0; k < 11; k++) acc[k] += pp[k];
            }
            float s = acc[10];
#pragma unroll
            for (int k = 0; k < 10; k++) s += bsh[k] * acc[k];
            Jl[j][c] = s;
        }
    }
    __syncthreads();

    if (j < 24) {
        float rx = thetas[n * 72 + j * 3 + 0];
        float ry = thetas[n * 72 + j * 3 + 1];
        float rz = thetas[n * 72 + j * 3 + 2];
        float th = sqrtf(rx * rx + ry * ry + rz * rz) + 1e-8f;
        float inv = 1.f / th;
        float hx = rx * inv, hy = ry * inv, hz = rz * inv;
        float ct = cosf(th), st = sinf(th), omc = 1.f - ct;
        float R[3][3];
        R[0][0] = ct + omc * hx * hx;
        R[0][1] = omc * hx * hy - st * hz;
        R[0][2] = omc * hx * hz + st * hy;
        R[1][0] = omc * hx * hy + st * hz;
        R[1][1] = ct + omc * hy * hy;
        R[1][2] = omc * hy * hz - st * hx;
        R[2][0] = omc * hx * hz - st * hy;
        R[2][1] = omc * hy * hz + st * hx;
        R[2][2] = ct + omc * hz * hz;

        if (j >= 1) {
            float* lp = &lr[(j - 1) * 9];
#pragma unroll
            for (int r = 0; r < 3; r++)
#pragma unroll
                for (int c = 0; c < 3; c++)
                    lp[r * 3 + c] = R[r][c] - ((r == c) ? 1.f : 0.f);
        }
        float tx, ty, tz;
        if (j == 0) { tx = Jl[0][0]; ty = Jl[0][1]; tz = Jl[0][2]; }
        else {
            int p = c_par[j];
            tx = Jl[j][0] - Jl[p][0];
            ty = Jl[j][1] - Jl[p][1];
            tz = Jl[j][2] - Jl[p][2];
        }
#pragma unroll
        for (int r = 0; r < 3; r++) {
            A[j][r * 4 + 0] = R[r][0];
            A[j][r * 4 + 1] = R[r][1];
            A[j][r * 4 + 2] = R[r][2];
        }
        A[j][3] = tx; A[j][7] = ty; A[j][11] = tz;
    }
    __syncthreads();

    if (threadIdx.x == 0) {
#pragma unroll
        for (int q = 0; q < 12; q++) Gs[0][q] = A[0][q];
        for (int i = 1; i < 24; i++) {
            int p = c_par[i];
#pragma unroll
            for (int r = 0; r < 3; r++) {
                float g0 = Gs[p][r * 4 + 0], g1 = Gs[p][r * 4 + 1];
                float g2 = Gs[p][r * 4 + 2], g3 = Gs[p][r * 4 + 3];
#pragma unroll
                for (int c = 0; c < 4; c++) {
                    float s = g0 * A[i][0 * 4 + c] + g1 * A[i][1 * 4 + c] +
                              g2 * A[i][2 * 4 + c];
                    if (c == 3) s += g3;
                    Gs[i][r * 4 + c] = s;
                }
            }
        }
    }
    for (int k = threadIdx.x; k < KDIM; k += 64) {
        float val;
        if (k < 10)       val = bsh[k];
        else if (k == 10) val = 1.f;
        else if (k < 218) val = lr[k - 11];
        else              val = 0.f;
        A_bf[(size_t)n * KDIM + k] = f2b(val);
    }
    __syncthreads();

    if (j < 24) {
        float jx = Jl[j][0], jy = Jl[j][1], jz = Jl[j][2];
        float* gp = Gout + (size_t)n * 288 + j * 12;
#pragma unroll
        for (int r = 0; r < 3; r++) {
            float r0 = Gs[j][r * 4 + 0], r1 = Gs[j][r * 4 + 1];
            float r2 = Gs[j][r * 4 + 2], t = Gs[j][r * 4 + 3];
            gp[r * 4 + 0] = r0;
            gp[r * 4 + 1] = r1;
            gp[r * 4 + 2] = r2;
            gp[r * 4 + 3] = t - (r0 * jx + r1 * jy + r2 * jz);
        }
    }
}

// ---------------------------------------------------------------------------
// K3G: MFMA GEMM  (R4 version, 64-sample m-blocks: B2 streamed only 8x)
__global__ void __launch_bounds__(256)
k3g(const unsigned short* __restrict__ A_bf,
    const unsigned short* __restrict__ B2,
    unsigned short* __restrict__ vposed) {
    const int wave = threadIdx.x >> 6, lane = threadIdx.x & 63;
    const int ln = lane & 15, q = lane >> 4;
    const int m0 = blockIdx.y * 64 + wave * 16;
    const int nt0 = blockIdx.x * 12;

    short8 a[7];
    {
        const int row = m0 + ln;
#pragma unroll
        for (int kc = 0; kc < 7; kc++)
            a[kc] = *(const short8*)(A_bf + (size_t)row * KDIM + kc * 32 + q * 8);
    }
    for (int t = 0; t < 12; t++) {
        const int nt = nt0 + t;
        float4v acc = {0.f, 0.f, 0.f, 0.f};
#pragma unroll
        for (int kc = 0; kc < 7; kc++) {
            short8 b = *(const short8*)(B2 +
                (((size_t)kc * NT + nt) * 16 + ln) * 32 + q * 8);
            acc = __builtin_amdgcn_mfma_f32_16x16x32_bf16(a[kc], b, acc, 0, 0, 0);
        }
        const int np = nt * 16 + ln;
#pragma unroll
        for (int r = 0; r < 4; r++) {
            int m = m0 + q * 4 + r;
            vposed[(size_t)m * NPRIME + np] = f2b(acc[r]);
        }
    }
}

// ---------------------------------------------------------------------------
// K3L: LBS.  (R4 best version: 4 verts/lane, no-LDS, readfirstlane sample,
// grid (128,27).)
__global__ void __launch_bounds__(256)
k3l(const float* __restrict__ trans,
    const unsigned short* __restrict__ vposed,
    const float* __restrict__ w_t,
    const float* __restrict__ G_ws,
    float* __restrict__ out) {
    const int tid = threadIdx.x;
    const int lane = tid & 63;
    const int nu = __builtin_amdgcn_readfirstlane(blockIdx.x * 4 + (tid >> 6));
    const int v4 = blockIdx.y * 256 + lane * 4;

    const float* gp = G_ws + (size_t)nu * 288;
    const float t0 = trans[nu * 3 + 0];
    const float t1 = trans[nu * 3 + 1];
    const float t2 = trans[nu * 3 + 2];

    float vp[3][4];
#pragma unroll
    for (int c = 0; c < 3; c++) {
        uint2 u = *(const uint2*)(vposed + (size_t)nu * NPRIME + c * NVP + v4);
        vp[c][0] = b2f((unsigned short)(u.x & 0xFFFF));
        vp[c][1] = b2f((unsigned short)(u.x >> 16));
        vp[c][2] = b2f((unsigned short)(u.y & 0xFFFF));
        vp[c][3] = b2f((unsigned short)(u.y >> 16));
    }

    float o[3][4];
#pragma unroll
    for (int c = 0; c < 3; c++)
#pragma unroll
        for (int i = 0; i < 4; i++) o[c][i] = 0.f;

    for (int j = 0; j < NJ; j++) {
        float4 w4 = *(const float4*)(w_t + (size_t)j * NVP + v4);
        float wv[4] = {w4.x, w4.y, w4.z, w4.w};
        const float4* g4 = (const float4*)(gp + j * 12);    // uniform loads
        float4 g0 = g4[0], g1 = g4[1], g2 = g4[2];
#pragma unroll
        for (int i = 0; i < 4; i++) {
            float x = vp[0][i], y = vp[1][i], z = vp[2][i];
            float r0 = g0.x * x + g0.y * y + g0.z * z + g0.w;
            float r1 = g1.x * x + g1.y * y + g1.z * z + g1.w;
            float r2 = g2.x * x + g2.y * y + g2.z * z + g2.w;
            o[0][i] += wv[i] * r0;
            o[1][i] += wv[i] * r1;
            o[2][i] += wv[i] * r2;
        }
    }

    {
        float* op = out + ((size_t)nu * NV + v4) * 3;
#pragma unroll
        for (int i = 0; i < 4; i++) {
            if (v4 + i < NV) {
                op[i * 3 + 0] = o[0][i] + t0;
                op[i * 3 + 1] = o[1][i] + t1;
                op[i * 3 + 2] = o[2][i] + t2;
            }
        }
    }
}

// ---------------------------------------------------------------------------
// K4: joints reduction.  R4 structure (one reduce per wave, 1728-vert chunks,
// 4 atomics per output address) with ONE delta: 2 samples per block — halves
// the jr_t L2 re-read (340 -> 170 MB).  R9's chunked-LDS version reverted
// (reduce-chain amplification + 27-way atomic contention caused 111 us).
__global__ void __launch_bounds__(256)
k4_joints_t(const float* __restrict__ result,
            const float* __restrict__ jr_t,
            float* __restrict__ outj) {
    const int n0 = blockIdx.x * 2;
    const int ch = blockIdx.y;
    const int wid = threadIdx.x >> 6, lane = threadIdx.x & 63;
    const int j0 = wid * 6;
    const int v0 = ch * 1728;
    int vend = v0 + 1728; if (vend > NV) vend = NV;

    float accA[18], accB[18];
#pragma unroll
    for (int q = 0; q < 18; q++) { accA[q] = 0.f; accB[q] = 0.f; }

    const float* ra = result + (size_t)n0 * NV * 3;
    const float* rb = result + (size_t)(n0 + 1) * NV * 3;
    for (int v = v0 + lane; v < vend; v += 64) {
        float w[6];
#pragma unroll
        for (int jj = 0; jj < 6; jj++)
            w[jj] = jr_t[(size_t)(j0 + jj) * NVP + v];
        float a0 = ra[v * 3 + 0], a1 = ra[v * 3 + 1], a2 = ra[v * 3 + 2];
        float b0 = rb[v * 3 + 0], b1 = rb[v * 3 + 1], b2 = rb[v * 3 + 2];
#pragma unroll
        for (int jj = 0; jj < 6; jj++) {
            accA[jj * 3 + 0] += w[jj] * a0;
            accA[jj * 3 + 1] += w[jj] * a1;
            accA[jj * 3 + 2] += w[jj] * a2;
            accB[jj * 3 + 0] += w[jj] * b0;
            accB[jj * 3 + 1] += w[jj] * b1;
            accB[jj * 3 + 2] += w[jj] * b2;
        }
    }
#pragma unroll
    for (int q = 0; q < 18; q++) {
        float x = accA[q];
        for (int off = 32; off > 0; off >>= 1) x += __shfl_down(x, off);
        accA[q] = x;
        float y = accB[q];
        for (int off = 32; off > 0; off >>= 1) y += __shfl_down(y, off);
        accB[q] = y;
    }
    if (lane == 0) {
#pragma unroll
        for (int q = 0; q < 18; q++) {
            atomicAdd(&outj[(size_t)n0 * 72 + j0 * 3 + q], accA[q]);
            atomicAdd(&outj[(size_t)(n0 + 1) * 72 + j0 * 3 + q], accB[q]);
        }
    }
}

// ---------------------------------------------------------------------------
extern "C" void kernel_launch(void* const* d_in, const int* in_sizes, int n_in,
                              void* d_out, int out_size, void* d_ws, size_t ws_size,
                              hipStream_t stream) {
    const float* betas     = (const float*)d_in[0];
    const float* thetas    = (const float*)d_in[1];
    const float* trans     = (const float*)d_in[2];
    const float* v_templ   = (const float*)d_in[3];
    const float* shapedirs = (const float*)d_in[4];
    const float* posedirs  = (const float*)d_in[5];
    const float* Jreg      = (const float*)d_in[6];
    const float* jointreg  = (const float*)d_in[7];
    const float* weights   = (const float*)d_in[8];

    float* out = (float*)d_out;       // fp32: result [N,V,3] then joints [N,24,3]
    const int N = in_sizes[0] / 10;   // 512

    // ws layout
    float* ws    = (float*)d_ws;
    float* SD_Jp = ws;                                   // 8*72*11 = 6336 (+pad) -> 6400
    float* G_ws  = ws + 6400;                            // N*288
    float* w_t   = G_ws + (size_t)N * 288;               // 24*NVP
    float* jr_t  = w_t + 24 * NVP;                       // 24*NVP
    unsigned short* A_bf = (unsigned short*)(jr_t + 24 * NVP);      // 512*224
    unsigned short* B2   = A_bf + (size_t)512 * KDIM;               // 7*NT*512
    unsigned short* vpos = B2 + (size_t)7 * NT * 512;               // 512*NPRIME

    float* outj = out + (size_t)N * NV * 3;

    dim3 g1(72, 8);
    k1_regress<<<g1, 256, 0, stream>>>(Jreg, shapedirs, v_templ, SD_Jp);
    k2_fk<<<N, 64, 0, stream>>>(betas, thetas, SD_Jp, G_ws, A_bf, outj);

    const int B2_N = 7 * NT * 16 * 32;
    int t_total = B2_N + (24 + 24) * NVP;
    t_pack<<<(t_total + 255) / 256, 256, 0, stream>>>(
        posedirs, weights, jointreg, shapedirs, v_templ,
        B2, w_t, jr_t);

    dim3 gg(NT / 12, N / 64);     // (108, 8)
    k3g<<<gg, 256, 0, stream>>>(A_bf, B2, vpos);

    dim3 gl(N / 4, NVP / 256);    // (128, 27) = 3456 blocks
    k3l<<<gl, 256, 0, stream>>>(trans, vpos, w_t, G_ws, out);

    dim3 g4(N / 2, 4);            // (256, 4) = 1024 blocks
    k4_joints_t<<<g4, 256, 0, stream>>>(out, jr_t, outj);
}

// Round 11
// 196.334 us; speedup vs baseline: 1.3565x; 1.0120x over previous
//
#include <hip/hip_runtime.h>
#include <hip/hip_bf16.h>
#include <math.h>

#define NJ 24
#define NV 6890
#define NVP 6912          // padded vertex count (27*256)
#define NPRIME 20736      // 3*NVP, GEMM N dimension
#define NT 1296           // NPRIME/16 n-tiles
#define KDIM 224          // padded K: [0..9]=betas/sd, [10]=1/vt, [11..217]=lrot/pd, rest 0

__constant__ int c_par[24] = {0, 0, 0, 0, 1, 2, 3, 4, 5, 6, 7, 8, 9, 9, 9,
                              12, 13, 14, 16, 17, 18, 19, 20, 21};

typedef __attribute__((ext_vector_type(8))) short short8;
typedef __attribute__((ext_vector_type(4))) float float4v;

__device__ __forceinline__ unsigned short f2b(float x) {
    __hip_bfloat16 h = __float2bfloat16(x);
    return *reinterpret_cast<unsigned short*>(&h);
}
__device__ __forceinline__ float b2f(unsigned short u) {
    unsigned int w = ((unsigned int)u) << 16;
    return __uint_as_float(w);
}

// ---------------------------------------------------------------------------
// T: pack kernel (B2 + w_t + jr_t).  (unchanged)
__global__ void t_pack(const float* __restrict__ pd,
                       const float* __restrict__ W,
                       const float* __restrict__ jr,
                       const float* __restrict__ sd,
                       const float* __restrict__ vt,
                       unsigned short* __restrict__ B2,
                       float* __restrict__ w_t,
                       float* __restrict__ jr_t) {
    int idx = blockIdx.x * 256 + threadIdx.x;
    const int B2_N = 7 * NT * 16 * 32;        // 4,644,864
    if (idx < B2_N) {
        int kk = idx & 31;
        int ln = (idx >> 5) & 15;
        int rest = idx >> 9;                  // nt + NT*kc
        int nt = rest % NT, kc = rest / NT;
        int k = kc * 32 + kk;
        int np = nt * 16 + ln;
        int c = np / NVP, v = np - c * NVP;
        float val = 0.f;
        if (v < NV) {
            if (k < 10)       val = sd[(size_t)v * 30 + c * 10 + k];
            else if (k == 10) val = vt[v * 3 + c];
            else if (k < 218) val = pd[(size_t)v * 621 + c * 207 + (k - 11)];
        }
        B2[idx] = f2b(val);
        return;
    }
    idx -= B2_N;
    if (idx < 24 * NVP) {
        int j = idx / NVP, v = idx % NVP;
        if (v < NV) w_t[(size_t)j * NVP + v] = W[(size_t)v * 24 + j];
        return;
    }
    idx -= 24 * NVP;
    if (idx < 24 * NVP) {
        int j = idx / NVP, v = idx % NVP;
        if (v < NV) jr_t[(size_t)j * NVP + v] = jr[(size_t)v * 24 + j];
        return;
    }
}

// ---------------------------------------------------------------------------
// K1: fold J_regressor into shapedirs / v_template.  (unchanged, grid (72,8))
__global__ void k1_regress(const float* __restrict__ Jreg,
                           const float* __restrict__ sd,
                           const float* __restrict__ vt,
                           float* __restrict__ SD_Jp) {
    const int jc = blockIdx.x;            // 0..71
    const int ch = blockIdx.y;            // 0..7
    const int j = jc / 3, c = jc % 3;
    const int v0 = ch * 864;
    int vend = v0 + 864; if (vend > NV) vend = NV;

    float acc[11];
#pragma unroll
    for (int k = 0; k < 11; k++) acc[k] = 0.f;

    for (int v = v0 + threadIdx.x; v < vend; v += 256) {
        float r = Jreg[j * NV + v];
        const float* sp = sd + (size_t)v * 30 + c * 10;
#pragma unroll
        for (int k = 0; k < 10; k++) acc[k] += r * sp[k];
        acc[10] += r * vt[v * 3 + c];
    }
#pragma unroll
    for (int k = 0; k < 11; k++) {
        float x = acc[k];
        for (int off = 32; off > 0; off >>= 1) x += __shfl_down(x, off);
        acc[k] = x;
    }
    __shared__ float red[4][11];
    int lane = threadIdx.x & 63, wid = threadIdx.x >> 6;
    if (lane == 0) {
#pragma unroll
        for (int k = 0; k < 11; k++) red[wid][k] = acc[k];
    }
    __syncthreads();
    if (threadIdx.x == 0) {
        float* op = SD_Jp + ((size_t)ch * 72 + jc) * 11;
#pragma unroll
        for (int k = 0; k < 11; k++)
            op[k] = red[0][k] + red[1][k] + red[2][k] + red[3][k];
    }
}

// ---------------------------------------------------------------------------
// K2: per-sample joints + rodrigues + FK + A_bf pack.  (unchanged)
__global__ void k2_fk(const float* __restrict__ betas,
                      const float* __restrict__ thetas,
                      const float* __restrict__ SD_Jp,
                      float* __restrict__ Gout,
                      unsigned short* __restrict__ A_bf,
                      float* __restrict__ outj) {
    int n = blockIdx.x;
    int j = threadIdx.x;

    __shared__ float bsh[10];
    __shared__ float Jl[24][3];
    __shared__ float A[24][12];
    __shared__ float Gs[24][12];
    __shared__ float lr[208];     // lrotmin staging for A_bf pack

    if (threadIdx.x < 10) bsh[threadIdx.x] = betas[n * 10 + threadIdx.x];
    if (threadIdx.x == 0) lr[207] = 0.f;
    for (int q = threadIdx.x; q < 72; q += 64) outj[(size_t)n * 72 + q] = 0.f;
    __syncthreads();

    if (j < 24) {
#pragma unroll
        for (int c = 0; c < 3; c++) {
            float acc[11];
#pragma unroll
            for (int k = 0; k < 11; k++) acc[k] = 0.f;
#pragma unroll
            for (int ch = 0; ch < 8; ch++) {
                const float* pp = SD_Jp + ((size_t)ch * 72 + j * 3 + c) * 11;
#pragma unroll
                for (int k = 0; k < 11; k++) acc[k] += pp[k];
            }
            float s = acc[10];
#pragma unroll
            for (int k = 0; k < 10; k++) s += bsh[k] * acc[k];
            Jl[j][c] = s;
        }
    }
    __syncthreads();

    if (j < 24) {
        float rx = thetas[n * 72 + j * 3 + 0];
        float ry = thetas[n * 72 + j * 3 + 1];
        float rz = thetas[n * 72 + j * 3 + 2];
        float th = sqrtf(rx * rx + ry * ry + rz * rz) + 1e-8f;
        float inv = 1.f / th;
        float hx = rx * inv, hy = ry * inv, hz = rz * inv;
        float ct = cosf(th), st = sinf(th), omc = 1.f - ct;
        float R[3][3];
        R[0][0] = ct + omc * hx * hx;
        R[0][1] = omc * hx * hy - st * hz;
        R[0][2] = omc * hx * hz + st * hy;
        R[1][0] = omc * hx * hy + st * hz;
        R[1][1] = ct + omc * hy * hy;
        R[1][2] = omc * hy * hz - st * hx;
        R[2][0] = omc * hx * hz - st * hy;
        R[2][1] = omc * hy * hz + st * hx;
        R[2][2] = ct + omc * hz * hz;

        if (j >= 1) {
            float* lp = &lr[(j - 1) * 9];
#pragma unroll
            for (int r = 0; r < 3; r++)
#pragma unroll
                for (int c = 0; c < 3; c++)
                    lp[r * 3 + c] = R[r][c] - ((r == c) ? 1.f : 0.f);
        }
        float tx, ty, tz;
        if (j == 0) { tx = Jl[0][0]; ty = Jl[0][1]; tz = Jl[0][2]; }
        else {
            int p = c_par[j];
            tx = Jl[j][0] - Jl[p][0];
            ty = Jl[j][1] - Jl[p][1];
            tz = Jl[j][2] - Jl[p][2];
        }
#pragma unroll
        for (int r = 0; r < 3; r++) {
            A[j][r * 4 + 0] = R[r][0];
            A[j][r * 4 + 1] = R[r][1];
            A[j][r * 4 + 2] = R[r][2];
        }
        A[j][3] = tx; A[j][7] = ty; A[j][11] = tz;
    }
    __syncthreads();

    if (threadIdx.x == 0) {
#pragma unroll
        for (int q = 0; q < 12; q++) Gs[0][q] = A[0][q];
        for (int i = 1; i < 24; i++) {
            int p = c_par[i];
#pragma unroll
            for (int r = 0; r < 3; r++) {
                float g0 = Gs[p][r * 4 + 0], g1 = Gs[p][r * 4 + 1];
                float g2 = Gs[p][r * 4 + 2], g3 = Gs[p][r * 4 + 3];
#pragma unroll
                for (int c = 0; c < 4; c++) {
                    float s = g0 * A[i][0 * 4 + c] + g1 * A[i][1 * 4 + c] +
                              g2 * A[i][2 * 4 + c];
                    if (c == 3) s += g3;
                    Gs[i][r * 4 + c] = s;
                }
            }
        }
    }
    for (int k = threadIdx.x; k < KDIM; k += 64) {
        float val;
        if (k < 10)       val = bsh[k];
        else if (k == 10) val = 1.f;
        else if (k < 218) val = lr[k - 11];
        else              val = 0.f;
        A_bf[(size_t)n * KDIM + k] = f2b(val);
    }
    __syncthreads();

    if (j < 24) {
        float jx = Jl[j][0], jy = Jl[j][1], jz = Jl[j][2];
        float* gp = Gout + (size_t)n * 288 + j * 12;
#pragma unroll
        for (int r = 0; r < 3; r++) {
            float r0 = Gs[j][r * 4 + 0], r1 = Gs[j][r * 4 + 1];
            float r2 = Gs[j][r * 4 + 2], t = Gs[j][r * 4 + 3];
            gp[r * 4 + 0] = r0;
            gp[r * 4 + 1] = r1;
            gp[r * 4 + 2] = r2;
            gp[r * 4 + 3] = t - (r0 * jx + r1 * jy + r2 * jz);
        }
    }
}

// ---------------------------------------------------------------------------
// K3G: MFMA GEMM.  Delta vs R10: 6 n-tiles/block (was 12) -> grid (216,8)
// = 1728 blocks (6.75/CU, was 3.4/CU under-coverage).  A_bf reload doubles
// but is 229 KB L2-resident.
__global__ void __launch_bounds__(256)
k3g(const unsigned short* __restrict__ A_bf,
    const unsigned short* __restrict__ B2,
    unsigned short* __restrict__ vposed) {
    const int wave = threadIdx.x >> 6, lane = threadIdx.x & 63;
    const int ln = lane & 15, q = lane >> 4;
    const int m0 = blockIdx.y * 64 + wave * 16;
    const int nt0 = blockIdx.x * 6;

    short8 a[7];
    {
        const int row = m0 + ln;
#pragma unroll
        for (int kc = 0; kc < 7; kc++)
            a[kc] = *(const short8*)(A_bf + (size_t)row * KDIM + kc * 32 + q * 8);
    }
    for (int t = 0; t < 6; t++) {
        const int nt = nt0 + t;
        float4v acc = {0.f, 0.f, 0.f, 0.f};
#pragma unroll
        for (int kc = 0; kc < 7; kc++) {
            short8 b = *(const short8*)(B2 +
                (((size_t)kc * NT + nt) * 16 + ln) * 32 + q * 8);
            acc = __builtin_amdgcn_mfma_f32_16x16x32_bf16(a[kc], b, acc, 0, 0, 0);
        }
        const int np = nt * 16 + ln;
#pragma unroll
        for (int r = 0; r < 4; r++) {
            int m = m0 + q * 4 + r;
            vposed[(size_t)m * NPRIME + np] = f2b(acc[r]);
        }
    }
}

// ---------------------------------------------------------------------------
// K3L: LBS.  (R4 structure.)  Delta vs R10: #pragma unroll 2 on the j-loop —
// ~23 us of the 38 us is exposed w_t L2 latency (VALU floor ~15 us); unroll-2
// keeps two w4 loads in flight per compute batch.  Capped at 2 to stay under
// the 64-VGPR occupancy step (R5 lesson: bigger live state inverts the gain).
__global__ void __launch_bounds__(256)
k3l(const float* __restrict__ trans,
    const unsigned short* __restrict__ vposed,
    const float* __restrict__ w_t,
    const float* __restrict__ G_ws,
    float* __restrict__ out) {
    const int tid = threadIdx.x;
    const int lane = tid & 63;
    const int nu = __builtin_amdgcn_readfirstlane(blockIdx.x * 4 + (tid >> 6));
    const int v4 = blockIdx.y * 256 + lane * 4;

    const float* gp = G_ws + (size_t)nu * 288;
    const float t0 = trans[nu * 3 + 0];
    const float t1 = trans[nu * 3 + 1];
    const float t2 = trans[nu * 3 + 2];

    float vp[3][4];
#pragma unroll
    for (int c = 0; c < 3; c++) {
        uint2 u = *(const uint2*)(vposed + (size_t)nu * NPRIME + c * NVP + v4);
        vp[c][0] = b2f((unsigned short)(u.x & 0xFFFF));
        vp[c][1] = b2f((unsigned short)(u.x >> 16));
        vp[c][2] = b2f((unsigned short)(u.y & 0xFFFF));
        vp[c][3] = b2f((unsigned short)(u.y >> 16));
    }

    float o[3][4];
#pragma unroll
    for (int c = 0; c < 3; c++)
#pragma unroll
        for (int i = 0; i < 4; i++) o[c][i] = 0.f;

#pragma unroll 2
    for (int j = 0; j < NJ; j++) {
        float4 w4 = *(const float4*)(w_t + (size_t)j * NVP + v4);
        float wv[4] = {w4.x, w4.y, w4.z, w4.w};
        const float4* g4 = (const float4*)(gp + j * 12);    // uniform loads
        float4 g0 = g4[0], g1 = g4[1], g2 = g4[2];
#pragma unroll
        for (int i = 0; i < 4; i++) {
            float x = vp[0][i], y = vp[1][i], z = vp[2][i];
            float r0 = g0.x * x + g0.y * y + g0.z * z + g0.w;
            float r1 = g1.x * x + g1.y * y + g1.z * z + g1.w;
            float r2 = g2.x * x + g2.y * y + g2.z * z + g2.w;
            o[0][i] += wv[i] * r0;
            o[1][i] += wv[i] * r1;
            o[2][i] += wv[i] * r2;
        }
    }

    {
        float* op = out + ((size_t)nu * NV + v4) * 3;
#pragma unroll
        for (int i = 0; i < 4; i++) {
            if (v4 + i < NV) {
                op[i * 3 + 0] = o[0][i] + t0;
                op[i * 3 + 1] = o[1][i] + t1;
                op[i * 3 + 2] = o[2][i] + t2;
            }
        }
    }
}

// ---------------------------------------------------------------------------
// K4: joints reduction.  (R10 version: 2 samples/block, grid (N/2,4).)
__global__ void __launch_bounds__(256)
k4_joints_t(const float* __restrict__ result,
            const float* __restrict__ jr_t,
            float* __restrict__ outj) {
    const int n0 = blockIdx.x * 2;
    const int ch = blockIdx.y;
    const int wid = threadIdx.x >> 6, lane = threadIdx.x & 63;
    const int j0 = wid * 6;
    const int v0 = ch * 1728;
    int vend = v0 + 1728; if (vend > NV) vend = NV;

    float accA[18], accB[18];
#pragma unroll
    for (int q = 0; q < 18; q++) { accA[q] = 0.f; accB[q] = 0.f; }

    const float* ra = result + (size_t)n0 * NV * 3;
    const float* rb = result + (size_t)(n0 + 1) * NV * 3;
    for (int v = v0 + lane; v < vend; v += 64) {
        float w[6];
#pragma unroll
        for (int jj = 0; jj < 6; jj++)
            w[jj] = jr_t[(size_t)(j0 + jj) * NVP + v];
        float a0 = ra[v * 3 + 0], a1 = ra[v * 3 + 1], a2 = ra[v * 3 + 2];
        float b0 = rb[v * 3 + 0], b1 = rb[v * 3 + 1], b2 = rb[v * 3 + 2];
#pragma unroll
        for (int jj = 0; jj < 6; jj++) {
            accA[jj * 3 + 0] += w[jj] * a0;
            accA[jj * 3 + 1] += w[jj] * a1;
            accA[jj * 3 + 2] += w[jj] * a2;
            accB[jj * 3 + 0] += w[jj] * b0;
            accB[jj * 3 + 1] += w[jj] * b1;
            accB[jj * 3 + 2] += w[jj] * b2;
        }
    }
#pragma unroll
    for (int q = 0; q < 18; q++) {
        float x = accA[q];
        for (int off = 32; off > 0; off >>= 1) x += __shfl_down(x, off);
        accA[q] = x;
        float y = accB[q];
        for (int off = 32; off > 0; off >>= 1) y += __shfl_down(y, off);
        accB[q] = y;
    }
    if (lane == 0) {
#pragma unroll
        for (int q = 0; q < 18; q++) {
            atomicAdd(&outj[(size_t)n0 * 72 + j0 * 3 + q], accA[q]);
            atomicAdd(&outj[(size_t)(n0 + 1) * 72 + j0 * 3 + q], accB[q]);
        }
    }
}

// ---------------------------------------------------------------------------
extern "C" void kernel_launch(void* const* d_in, const int* in_sizes, int n_in,
                              void* d_out, int out_size, void* d_ws, size_t ws_size,
                              hipStream_t stream) {
    const float* betas     = (const float*)d_in[0];
    const float* thetas    = (const float*)d_in[1];
    const float* trans     = (const float*)d_in[2];
    const float* v_templ   = (const float*)d_in[3];
    const float* shapedirs = (const float*)d_in[4];
    const float* posedirs  = (const float*)d_in[5];
    const float* Jreg      = (const float*)d_in[6];
    const float* jointreg  = (const float*)d_in[7];
    const float* weights   = (const float*)d_in[8];

    float* out = (float*)d_out;       // fp32: result [N,V,3] then joints [N,24,3]
    const int N = in_sizes[0] / 10;   // 512

    // ws layout
    float* ws    = (float*)d_ws;
    float* SD_Jp = ws;                                   // 8*72*11 = 6336 (+pad) -> 6400
    float* G_ws  = ws + 6400;                            // N*288
    float* w_t   = G_ws + (size_t)N * 288;               // 24*NVP
    float* jr_t  = w_t + 24 * NVP;                       // 24*NVP
    unsigned short* A_bf = (unsigned short*)(jr_t + 24 * NVP);      // 512*224
    unsigned short* B2   = A_bf + (size_t)512 * KDIM;               // 7*NT*512
    unsigned short* vpos = B2 + (size_t)7 * NT * 512;               // 512*NPRIME

    float* outj = out + (size_t)N * NV * 3;

    dim3 g1(72, 8);
    k1_regress<<<g1, 256, 0, stream>>>(Jreg, shapedirs, v_templ, SD_Jp);
    k2_fk<<<N, 64, 0, stream>>>(betas, thetas, SD_Jp, G_ws, A_bf, outj);

    const int B2_N = 7 * NT * 16 * 32;
    int t_total = B2_N + (24 + 24) * NVP;
    t_pack<<<(t_total + 255) / 256, 256, 0, stream>>>(
        posedirs, weights, jointreg, shapedirs, v_templ,
        B2, w_t, jr_t);

    dim3 gg(NT / 6, N / 64);      // (216, 8) = 1728 blocks
    k3g<<<gg, 256, 0, stream>>>(A_bf, B2, vpos);

    dim3 gl(N / 4, NVP / 256);    // (128, 27) = 3456 blocks
    k3l<<<gl, 256, 0, stream>>>(trans, vpos, w_t, G_ws, out);

    dim3 g4(N / 2, 4);            // (256, 4) = 1024 blocks
    k4_joints_t<<<g4, 256, 0, stream>>>(out, jr_t, outj);
}